// Round 1
// baseline (4018.478 us; speedup 1.0000x reference)
//
#include <hip/hip_runtime.h>

// Problem constants (HARSpikingNet): T=128, B=512, D=512, H=2048, C=18
#define T_STEPS 128
#define BSZ     512
#define DDIM    512
#define HDIM    2048
#define CDIM    18

#define BT 64    // b-tile per workgroup
#define HT 64    // h-tile per workgroup
#define KC 64    // k-chunk staged in LDS per step

// Padded LDS strides (floats). Both are multiples of 4 (16B alignment for b128).
// Ws stride 516: consecutive h-rows are 4 banks apart -> 2-way conflict (free).
// Xs stride 68 : consecutive b-rows are 4 banks apart -> spread across 16 banks.
#define WS_STRIDE 516
#define XS_STRIDE 68

// Fused: input GEMM (x @ W_in^T + b_in) + LIF scan over T, emitting z at t=T-1.
// One WG per (64b x 64h) tile; W_in panel resident in LDS for all 128 steps.
__launch_bounds__(256, 1)
__global__ void snn_fused(const float* __restrict__ x,
                          const float* __restrict__ Win,
                          const float* __restrict__ bin,
                          unsigned char* __restrict__ z_ws) {
    extern __shared__ float lds[];
    float* Ws = lds;                    // [HT][WS_STRIDE]  = 64*516*4 = 132096 B
    float* Xs = lds + HT * WS_STRIDE;   // [BT][XS_STRIDE]  = 64*68*4  =  17408 B

    const int b0  = blockIdx.x * BT;    // 8 b-tiles
    const int h0  = blockIdx.y * HT;    // 32 h-tiles
    const int tid = threadIdx.x;
    const int tx  = tid & 15;           // h-group  (cols tx, tx+16, tx+32, tx+48)
    const int ty  = tid >> 4;           // b-group  (rows ty, ty+16, ty+32, ty+48)

    // ---- Load W_in tile (64 rows x 512 cols) into LDS, once. 32 float4/thread.
    #pragma unroll
    for (int m = 0; m < 32; ++m) {
        int idx = tid + 256 * m;        // float4 index in 64x512 tile
        int r   = idx >> 7;             // 128 float4 per row
        int c4  = idx & 127;
        float4 w = reinterpret_cast<const float4*>(Win + (size_t)(h0 + r) * DDIM)[c4];
        float* dst = &Ws[r * WS_STRIDE + c4 * 4];
        dst[0] = w.x; dst[1] = w.y; dst[2] = w.z; dst[3] = w.w;
    }

    // Per-thread bias for its 4 h-columns
    float bias[4];
    #pragma unroll
    for (int j = 0; j < 4; ++j) bias[j] = bin[h0 + tx + 16 * j];

    float v[4][4];
    #pragma unroll
    for (int i = 0; i < 4; ++i)
        #pragma unroll
        for (int j = 0; j < 4; ++j) v[i][j] = 0.0f;
    float z[4][4];

    for (int t = 0; t < T_STEPS; ++t) {
        float acc[4][4];
        #pragma unroll
        for (int i = 0; i < 4; ++i)
            #pragma unroll
            for (int j = 0; j < 4; ++j) acc[i][j] = 0.0f;

        for (int kc = 0; kc < DDIM / KC; ++kc) {
            __syncthreads();   // previous compute done reading Xs
            // ---- Stage x[t, b0:b0+64, kc*64:(kc+1)*64] -> LDS. 4 float4/thread.
            const float* xsrc = x + ((size_t)t * BSZ + b0) * DDIM + kc * KC;
            #pragma unroll
            for (int m = 0; m < 4; ++m) {
                int idx = tid + 256 * m;    // float4 index in 64x64 tile
                int r   = idx >> 4;         // 16 float4 per row
                int c4  = idx & 15;
                float4 xv = reinterpret_cast<const float4*>(xsrc + (size_t)r * DDIM)[c4];
                float* dst = &Xs[r * XS_STRIDE + c4 * 4];
                dst[0] = xv.x; dst[1] = xv.y; dst[2] = xv.z; dst[3] = xv.w;
            }
            __syncthreads();

            // ---- 4x4 register-blocked FMA over this k-chunk
            #pragma unroll
            for (int kq = 0; kq < KC / 4; ++kq) {
                float4 xv[4], wv[4];
                #pragma unroll
                for (int i = 0; i < 4; ++i)
                    xv[i] = *reinterpret_cast<const float4*>(&Xs[(ty + 16 * i) * XS_STRIDE + kq * 4]);
                #pragma unroll
                for (int j = 0; j < 4; ++j)
                    wv[j] = *reinterpret_cast<const float4*>(&Ws[(tx + 16 * j) * WS_STRIDE + kc * KC + kq * 4]);
                #pragma unroll
                for (int i = 0; i < 4; ++i)
                    #pragma unroll
                    for (int j = 0; j < 4; ++j) {
                        acc[i][j] = fmaf(xv[i].x, wv[j].x, acc[i][j]);
                        acc[i][j] = fmaf(xv[i].y, wv[j].y, acc[i][j]);
                        acc[i][j] = fmaf(xv[i].z, wv[j].z, acc[i][j]);
                        acc[i][j] = fmaf(xv[i].w, wv[j].w, acc[i][j]);
                    }
            }
        }

        // ---- LIF state update (v carried in registers across all T)
        #pragma unroll
        for (int i = 0; i < 4; ++i)
            #pragma unroll
            for (int j = 0; j < 4; ++j) {
                float vv = 0.9f * v[i][j] + (acc[i][j] + bias[j]);
                float zz = (vv - 1.0f) > 0.0f ? 1.0f : 0.0f;
                v[i][j] = vv - zz;
                z[i][j] = zz;
            }
    }

    // ---- Emit z at t = T-1 as bytes (0/1) to workspace
    #pragma unroll
    for (int i = 0; i < 4; ++i)
        #pragma unroll
        for (int j = 0; j < 4; ++j)
            z_ws[(size_t)(b0 + ty + 16 * i) * HDIM + (h0 + tx + 16 * j)] = (unsigned char)z[i][j];
}

// logits[b,c] = sum_h z[b,h] * W_out[c,h] + b_out[c].  One wave per (b,c).
__global__ void snn_out(const unsigned char* __restrict__ z,
                        const float* __restrict__ Wout,
                        const float* __restrict__ bout,
                        float* __restrict__ out) {
    int gtid = blockIdx.x * blockDim.x + threadIdx.x;
    int wave = gtid >> 6;
    int lane = threadIdx.x & 63;
    if (wave >= BSZ * CDIM) return;
    int b = wave / CDIM;
    int c = wave % CDIM;

    const unsigned char* zr = z + (size_t)b * HDIM;
    const float* wr = Wout + (size_t)c * HDIM;
    float s = 0.0f;
    #pragma unroll
    for (int m = 0; m < HDIM / 64; ++m) {
        int h = lane + 64 * m;
        s = fmaf((float)zr[h], wr[h], s);
    }
    #pragma unroll
    for (int off = 32; off > 0; off >>= 1) s += __shfl_down(s, off, 64);
    if (lane == 0) out[(size_t)b * CDIM + c] = s + bout[c];
}

extern "C" void kernel_launch(void* const* d_in, const int* in_sizes, int n_in,
                              void* d_out, int out_size, void* d_ws, size_t ws_size,
                              hipStream_t stream) {
    const float* x    = (const float*)d_in[0];   // [128,512,512]
    const float* Win  = (const float*)d_in[1];   // [2048,512]
    const float* bin  = (const float*)d_in[2];   // [2048]
    const float* Wout = (const float*)d_in[3];   // [18,2048]
    const float* bout = (const float*)d_in[4];   // [18]
    float* out = (float*)d_out;                  // [512,18]

    unsigned char* z_ws = (unsigned char*)d_ws;  // [512,2048] bytes (1 MB)

    dim3 grid1(BSZ / BT, HDIM / HT);             // 8 x 32 = 256 WGs (1/CU)
    size_t lds_bytes = (size_t)(HT * WS_STRIDE + BT * XS_STRIDE) * sizeof(float); // 149504
    snn_fused<<<grid1, 256, lds_bytes, stream>>>(x, Win, bin, z_ws);

    int waves = BSZ * CDIM;                      // 9216
    int blocks2 = (waves * 64) / 256;            // 2304
    snn_out<<<blocks2, 256, 0, stream>>>(z_ws, Wout, bout, out);
}

// Round 2
// 3134.013 us; speedup vs baseline: 1.2822x; 1.2822x over previous
//
#include <hip/hip_runtime.h>
#include <stdint.h>

// HARSpikingNet: T=128, B=512, D=512, H=2048, C=18
#define T_STEPS 128
#define BSZ     512
#define DDIM    512
#define HDIM    2048
#define CDIM    18

#define BT 64                       // b-tile per WG
#define HT 64                       // h-tile per WG
#define KC 32                       // k-chunk per stage
#define NCHUNKS_PER_T (DDIM / KC)   // 16
#define NCHUNK (T_STEPS * NCHUNKS_PER_T) // 2048
#define XBUF_FLOATS (BT * KC)       // 2048 floats = 8192 B per buffer
#define NBUF 3

typedef const __attribute__((address_space(1))) void gv_t;
typedef __attribute__((address_space(3))) void lv_t;

// Fused input-GEMM (x @ W_in^T + b_in) + LIF scan; z at t=T-1 -> z_ws bytes.
// 512 threads = 8 waves (2/SIMD). W^T resident in LDS [k][h] (128 KB, unpadded).
// x staged via global_load_lds (16B/lane) into 3 rotating 8KB buffers with
// counted vmcnt(1) + raw s_barrier (1 barrier/chunk, 2-chunk-deep pipeline).
// x columns are source-swizzled (seg ^= row&3) so compute-side xv reads hit
// disjoint banks while the LDS stays linear for global_load_lds.
__launch_bounds__(512, 2)
__global__ void snn_fused(const float* __restrict__ x,
                          const float* __restrict__ Win,
                          const float* __restrict__ bin,
                          unsigned char* __restrict__ z_ws) {
    __shared__ float WsT[DDIM * HT];           // [k][h]  131072 B
    __shared__ float Xs[NBUF * XBUF_FLOATS];   //          24576 B  (total 155648)

    const int tid  = threadIdx.x;
    const int lane = tid & 63;
    const int wave = tid >> 6;          // 0..7
    const int tx   = tid & 15;          // h cols: h0 + tx*4 + j
    const int ty   = tid >> 4;          // 0..31: b rows ty, ty+32
    const int b0   = blockIdx.x * BT;   // 8 b-tiles
    const int h0   = blockIdx.y * HT;   // 32 h-tiles

    // ---- One-time: load W tile transposed into LDS: WsT[k][h] = Win[h0+h][k]
    {
        const int h  = tid & 63;
        const int k4 = (tid >> 6) << 2;                  // 0,4,...,28
        const float* wrow = Win + (size_t)(h0 + h) * DDIM;
        #pragma unroll
        for (int m = 0; m < 16; ++m) {
            const int k = k4 + m * 32;
            float4 w = *(const float4*)(wrow + k);
            WsT[(k + 0) * HT + h] = w.x;
            WsT[(k + 1) * HT + h] = w.y;
            WsT[(k + 2) * HT + h] = w.z;
            WsT[(k + 3) * HT + h] = w.w;
        }
    }

    float bias[4];
    #pragma unroll
    for (int j = 0; j < 4; ++j) bias[j] = bin[h0 + tx * 4 + j];

    float v[2][4]   = {{0.f,0.f,0.f,0.f},{0.f,0.f,0.f,0.f}};
    float acc[2][4] = {{0.f,0.f,0.f,0.f},{0.f,0.f,0.f,0.f}};
    float zz[2][4]  = {{0.f,0.f,0.f,0.f},{0.f,0.f,0.f,0.f}};

    // Staging geometry: wave w stages rows 8w..8w+7 (1024 B = 64 lanes x 16 B).
    // Lane covers stored seg s=(lane&7) of row r=8w+(lane>>3); it FETCHES global
    // seg g = s ^ (r&3)  (source swizzle; LDS destination stays linear).
    const int sr = (wave << 3) + (lane >> 3);
    const int sg = ((lane & 7) ^ (sr & 3)) << 2;            // float offset
    const float* xsrc_base = x + (size_t)(b0 + sr) * DDIM + sg;

    __syncthreads();   // WsT visible to all

    #define STAGE(c, bufi) do {                                                 \
        const int t_ = (c) >> 4, kc_ = (c) & 15;                                \
        const float* src_ = xsrc_base + (size_t)t_ * (BSZ * DDIM) + kc_ * KC;   \
        void* dst_ = (void*)(Xs + (bufi) * XBUF_FLOATS + (wave << 8));          \
        __builtin_amdgcn_global_load_lds((gv_t*)src_, (lv_t*)dst_, 16, 0, 0);   \
    } while (0)

    STAGE(0, 0);
    STAGE(1, 1);

    const int m4 = (ty & 3) << 2;       // per-thread read-swizzle key
    int buf = 0;

    for (int c = 0; c < NCHUNK; ++c) {
        // my chunk-c stage retired when <=1 of my loads remain in flight
        asm volatile("s_waitcnt vmcnt(1)" ::: "memory");
        __builtin_amdgcn_s_barrier();
        __builtin_amdgcn_sched_barrier(0);

        if (c + 2 < NCHUNK) {
            int b2 = buf + 2; if (b2 >= NBUF) b2 -= NBUF;
            STAGE(c + 2, b2);
        }

        const float* xb = Xs + buf * XBUF_FLOATS;
        const float* wb = WsT + (c & 15) * (KC * HT);   // kc * 2048 floats

        #pragma unroll
        for (int kq = 0; kq < 8; ++kq) {
            const int xo = (kq << 2) ^ m4;   // swizzled seg of cols kq*4..+3
            float4 xv0 = *(const float4*)(xb + ty * KC + xo);
            float4 xv1 = *(const float4*)(xb + (ty + 32) * KC + xo);
            float4 w0  = *(const float4*)(wb + (kq * 4 + 0) * HT + tx * 4);
            float4 w1  = *(const float4*)(wb + (kq * 4 + 1) * HT + tx * 4);
            float4 w2  = *(const float4*)(wb + (kq * 4 + 2) * HT + tx * 4);
            float4 w3  = *(const float4*)(wb + (kq * 4 + 3) * HT + tx * 4);
            #define FMA8(W, C)                                   \
                acc[0][0] = fmaf(xv0.C, W.x, acc[0][0]);         \
                acc[0][1] = fmaf(xv0.C, W.y, acc[0][1]);         \
                acc[0][2] = fmaf(xv0.C, W.z, acc[0][2]);         \
                acc[0][3] = fmaf(xv0.C, W.w, acc[0][3]);         \
                acc[1][0] = fmaf(xv1.C, W.x, acc[1][0]);         \
                acc[1][1] = fmaf(xv1.C, W.y, acc[1][1]);         \
                acc[1][2] = fmaf(xv1.C, W.z, acc[1][2]);         \
                acc[1][3] = fmaf(xv1.C, W.w, acc[1][3]);
            FMA8(w0, x) FMA8(w1, y) FMA8(w2, z) FMA8(w3, w)
            #undef FMA8
        }

        if ((c & 15) == 15) {            // end of timestep: LIF update
            #pragma unroll
            for (int i = 0; i < 2; ++i)
                #pragma unroll
                for (int j = 0; j < 4; ++j) {
                    float vv = 0.9f * v[i][j] + (acc[i][j] + bias[j]);
                    float z1 = vv > 1.0f ? 1.0f : 0.0f;
                    v[i][j]  = vv - z1;
                    zz[i][j] = z1;
                    acc[i][j] = 0.0f;
                }
        }
        buf = (buf + 1 == NBUF) ? 0 : buf + 1;
    }

    // ---- emit z at t = T-1
    uchar4 o0 = make_uchar4((unsigned char)zz[0][0], (unsigned char)zz[0][1],
                            (unsigned char)zz[0][2], (unsigned char)zz[0][3]);
    uchar4 o1 = make_uchar4((unsigned char)zz[1][0], (unsigned char)zz[1][1],
                            (unsigned char)zz[1][2], (unsigned char)zz[1][3]);
    *(uchar4*)(z_ws + (size_t)(b0 + ty)      * HDIM + h0 + tx * 4) = o0;
    *(uchar4*)(z_ws + (size_t)(b0 + ty + 32) * HDIM + h0 + tx * 4) = o1;
    #undef STAGE
}

// logits[b,c] = sum_h z[b,h] * W_out[c,h] + b_out[c]. One wave per (b,c).
__global__ void snn_out(const unsigned char* __restrict__ z,
                        const float* __restrict__ Wout,
                        const float* __restrict__ bout,
                        float* __restrict__ out) {
    int gtid = blockIdx.x * blockDim.x + threadIdx.x;
    int wv   = gtid >> 6;
    int lane = threadIdx.x & 63;
    if (wv >= BSZ * CDIM) return;
    int b = wv / CDIM;
    int c = wv % CDIM;

    const unsigned char* zr = z + (size_t)b * HDIM;
    const float* wr = Wout + (size_t)c * HDIM;
    float s = 0.0f;
    #pragma unroll
    for (int m = 0; m < HDIM / 64; ++m) {
        int h = lane + 64 * m;
        s = fmaf((float)zr[h], wr[h], s);
    }
    #pragma unroll
    for (int off = 32; off > 0; off >>= 1) s += __shfl_down(s, off, 64);
    if (lane == 0) out[(size_t)b * CDIM + c] = s + bout[c];
}

extern "C" void kernel_launch(void* const* d_in, const int* in_sizes, int n_in,
                              void* d_out, int out_size, void* d_ws, size_t ws_size,
                              hipStream_t stream) {
    const float* x    = (const float*)d_in[0];   // [128,512,512]
    const float* Win  = (const float*)d_in[1];   // [2048,512]
    const float* bin  = (const float*)d_in[2];   // [2048]
    const float* Wout = (const float*)d_in[3];   // [18,2048]
    const float* bout = (const float*)d_in[4];   // [18]
    float* out = (float*)d_out;                  // [512,18]

    unsigned char* z_ws = (unsigned char*)d_ws;  // [512,2048] bytes

    dim3 grid1(BSZ / BT, HDIM / HT);             // 8 x 32 = 256 WGs (1/CU)
    snn_fused<<<grid1, 512, 0, stream>>>(x, Win, bin, z_ws);

    int waves = BSZ * CDIM;                      // 9216
    int blocks2 = (waves * 64) / 256;            // 2304
    snn_out<<<blocks2, 256, 0, stream>>>(z_ws, Wout, bout, out);
}